// Round 3
// baseline (304.551 us; speedup 1.0000x reference)
//
#include <hip/hip_runtime.h>

#define NBINS   256
#define B       64
#define NPB     786432          // 3*512*512 elements per batch
#define NF4     (NPB / 4)       // 196608 float4 per batch
#define BPB1    32              // k1 blocks per batch -> 2048 blocks, 24 iters/thread
#define BPB2    16              // k2 blocks per batch -> 1024 blocks, 24 iters/thread @512thr
#define T1      256
#define T2      512

// ---------------------------------------------------------------------------
// k1: per-block min/max partials. Dual accumulators break the fmin/fmax
//     dependency chain. Block 0 also zeroes the k3 completion counter
//     (ws is re-poisoned to 0xAA before every timed call).
// ---------------------------------------------------------------------------
__global__ __launch_bounds__(T1) void k_minmax(const float4* __restrict__ x,
                                               float* __restrict__ pmn,
                                               float* __restrict__ pmx,
                                               unsigned* __restrict__ counter) {
    if (blockIdx.x == 0 && threadIdx.x == 0) counter[0] = 0u;

    const int batch = blockIdx.x / BPB1;
    const int blk   = blockIdx.x % BPB1;
    const float4* p = x + (long long)batch * NF4;

    float mn0 = 3.402823466e38f, mx0 = -3.402823466e38f;
    float mn1 = 3.402823466e38f, mx1 = -3.402823466e38f;
    // NF4 / (BPB1*T1) = 24 exact; step by 2*stride with two accumulators
    const int stride = BPB1 * T1;
    int i = blk * T1 + threadIdx.x;
    #pragma unroll 4
    for (int it = 0; it < 12; ++it, i += 2 * stride) {
        float4 a = p[i];
        float4 b = p[i + stride];
        mn0 = fminf(mn0, fminf(fminf(a.x, a.y), fminf(a.z, a.w)));
        mx0 = fmaxf(mx0, fmaxf(fmaxf(a.x, a.y), fmaxf(a.z, a.w)));
        mn1 = fminf(mn1, fminf(fminf(b.x, b.y), fminf(b.z, b.w)));
        mx1 = fmaxf(mx1, fmaxf(fmaxf(b.x, b.y), fmaxf(b.z, b.w)));
    }
    float mn = fminf(mn0, mn1), mx = fmaxf(mx0, mx1);
    for (int o = 32; o > 0; o >>= 1) {
        mn = fminf(mn, __shfl_down(mn, o));
        mx = fmaxf(mx, __shfl_down(mx, o));
    }
    __shared__ float smn[4], smx[4];
    int wid = threadIdx.x >> 6;
    if ((threadIdx.x & 63) == 0) { smn[wid] = mn; smx[wid] = mx; }
    __syncthreads();
    if (threadIdx.x == 0) {
        pmn[blockIdx.x] = fminf(fminf(smn[0], smn[1]), fminf(smn[2], smn[3]));
        pmx[blockIdx.x] = fmaxf(fmaxf(smx[0], smx[1]), fmaxf(smx[2], smx[3]));
    }
}

// ---------------------------------------------------------------------------
// k2: per-block partial histogram, 512 threads (32 waves/CU: 4 blocks x 8
//     waves, 4x32KB=128KB LDS). 32 transposed replicas lh[bin*32+g], g =
//     lane%32 => bank == g always => conflict-free atomics (2-way lane/
//     lane+32 aliasing is free).
// ---------------------------------------------------------------------------
__global__ __launch_bounds__(T2) void k_hist(const float4* __restrict__ x,
                                             const float* __restrict__ pmn,
                                             const float* __restrict__ pmx,
                                             unsigned* __restrict__ part) {
    __shared__ unsigned lh[NBINS * 32];      // 32 KB
    __shared__ float s_lo, s_scale;

    const int batch = blockIdx.x / BPB2;
    const int blk   = blockIdx.x % BPB2;

    for (int i = threadIdx.x; i < NBINS * 32; i += T2) lh[i] = 0u;

    if (threadIdx.x < 64) {
        int l = threadIdx.x & 31;
        float mn = pmn[batch * BPB1 + l];
        float mx = pmx[batch * BPB1 + l];
        for (int o = 16; o > 0; o >>= 1) {
            mn = fminf(mn, __shfl_down(mn, o));
            mx = fmaxf(mx, __shfl_down(mx, o));
        }
        if (threadIdx.x == 0) {
            // Match reference: rng/lo selection, f32 divide then multiply.
            float rng = (mx > mn) ? (mx - mn) : 2.0f;
            s_lo      = (mx > mn) ? mn : (mn - 1.0f);
            s_scale   = (float)NBINS / rng;
        }
    }
    __syncthreads();

    const float lo    = s_lo;
    const float scale = s_scale;
    const int   g     = threadIdx.x & 31;
    const float4* p   = x + (long long)batch * NF4;

    // NF4 / (BPB2*T2) = 24 exact
    #pragma unroll 2
    for (int i = blk * T2 + threadIdx.x; i < NF4; i += BPB2 * T2) {
        float4 v = p[i];
        int i0 = min(max((int)((v.x - lo) * scale), 0), NBINS - 1);
        int i1 = min(max((int)((v.y - lo) * scale), 0), NBINS - 1);
        int i2 = min(max((int)((v.z - lo) * scale), 0), NBINS - 1);
        int i3 = min(max((int)((v.w - lo) * scale), 0), NBINS - 1);
        atomicAdd(&lh[i0 * 32 + g], 1u);
        atomicAdd(&lh[i1 * 32 + g], 1u);
        atomicAdd(&lh[i2 * 32 + g], 1u);
        atomicAdd(&lh[i3 * 32 + g], 1u);
    }
    __syncthreads();

    // Merge replicas for bin = tid (<256), rotated read: lane L reads bank
    // (j+L)%32 -> conflict-free. Coalesced partial-hist store.
    if (threadIdx.x < NBINS) {
        unsigned s = 0;
        #pragma unroll
        for (int j = 0; j < 32; ++j)
            s += lh[threadIdx.x * 32 + ((j + threadIdx.x) & 31)];
        part[blockIdx.x * NBINS + threadIdx.x] = s;
    }
}

// ---------------------------------------------------------------------------
// k3: 64 blocks, one per batch: sum 16 partials/bin, entropy reduce, write
//     ent[b]; last block to finish reduces the 64 entropies -> out[0].
// ---------------------------------------------------------------------------
__global__ __launch_bounds__(T1) void k_ent(const unsigned* __restrict__ part,
                                            float* __restrict__ ent,
                                            unsigned* __restrict__ counter,
                                            float* __restrict__ out) {
    const int b = blockIdx.x;
    unsigned c = 0;
    #pragma unroll
    for (int j = 0; j < BPB2; ++j)
        c += part[(b * BPB2 + j) * NBINS + threadIdx.x];

    float s = 0.0f;
    if (c) {
        float pv = (float)c * (1.0f / (float)NPB);
        s = pv * log2f(pv);
    }
    for (int o = 32; o > 0; o >>= 1) s += __shfl_down(s, o);
    __shared__ float sw[4];
    __shared__ int last;
    int wid = threadIdx.x >> 6;
    if ((threadIdx.x & 63) == 0) sw[wid] = s;
    __syncthreads();
    if (threadIdx.x == 0) {
        ent[b] = -(sw[0] + sw[1] + sw[2] + sw[3]);
        __threadfence();                       // release ent[b]
        unsigned old = atomicAdd(counter, 1u); // device-scope
        last = (old == B - 1) ? 1 : 0;
    }
    __syncthreads();
    if (last) {
        __threadfence();                       // acquire all ent[] writes
        if (threadIdx.x < 64) {
            float v = ent[threadIdx.x];
            for (int o = 32; o > 0; o >>= 1) v += __shfl_down(v, o);
            if (threadIdx.x == 0) out[0] = v * (1.0f / (float)B);
        }
    }
}

extern "C" void kernel_launch(void* const* d_in, const int* in_sizes, int n_in,
                              void* d_out, int out_size, void* d_ws, size_t ws_size,
                              hipStream_t stream) {
    const float* x = (const float*)d_in[0];
    float* out = (float*)d_out;

    float*    pmn  = (float*)d_ws;                       // 2048 f32
    float*    pmx  = pmn + B * BPB1;                     // 2048 f32
    unsigned* part = (unsigned*)(pmx + B * BPB1);        // 1024*256 u32
    float*    ent  = (float*)(part + B * BPB2 * NBINS);  // 64 f32
    unsigned* cnt  = (unsigned*)(ent + B);               // 1 u32

    hipLaunchKernelGGL(k_minmax, dim3(B * BPB1), dim3(T1), 0, stream,
                       (const float4*)x, pmn, pmx, cnt);
    hipLaunchKernelGGL(k_hist, dim3(B * BPB2), dim3(T2), 0, stream,
                       (const float4*)x, pmn, pmx, part);
    hipLaunchKernelGGL(k_ent, dim3(B), dim3(T1), 0, stream, part, ent, cnt, out);
}